// Round 13
// baseline (32083.310 us; speedup 1.0000x reference)
//
#include <hip/hip_runtime.h>

#define SEQ 65536
#define IN_DIM 64
#define H 128
#define G4 512
#define LOG2E 1.4426950408889634f

typedef _Float16 half_t;
typedef half_t half2_t __attribute__((ext_vector_type(2)));
typedef int    i4     __attribute__((ext_vector_type(4)));

__device__ __forceinline__ float fast_rcp(float x) { return __builtin_amdgcn_rcpf(x); }

__device__ __forceinline__ float exp2_fast(float x) {
#if __has_builtin(__builtin_amdgcn_exp2f)
    return __builtin_amdgcn_exp2f(x);
#else
    return exp2f(x);
#endif
}

// sigmoid of (u / log2e): u PRE-SCALED by log2e -> rcp(1+exp2(-u)).
__device__ __forceinline__ float sig2(float u) {
    return fast_rcp(1.f + exp2_fast(-u));
}

__device__ __forceinline__ float sigmoid_f(float x) {
    return sig2(x * LOG2E);
}

#if __has_builtin(__builtin_amdgcn_fdot2)
__device__ __forceinline__ float dot2i(int w, int h, float acc) {
    return __builtin_amdgcn_fdot2(__builtin_bit_cast(half2_t, w),
                                  __builtin_bit_cast(half2_t, h), acc, false);
}
#else
__device__ __forceinline__ float dot2i(int w, int h, float acc) {
    half2_t a = __builtin_bit_cast(half2_t, w);
    half2_t b = __builtin_bit_cast(half2_t, h);
    return acc + (float)a[0] * (float)b[0] + (float)a[1] * (float)b[1];
}
#endif

// two f32 -> one VGPR of packed 2xf16 (v_cvt_pkrtz_f16_f32)
__device__ __forceinline__ int pk(float a, float b) {
    return __builtin_bit_cast(int, __builtin_amdgcn_cvt_pkrtz(a, b));
}

// 8 fp32 -> int4 of packed half2s, scaled by s
__device__ __forceinline__ i4 cvt8i_s(const float* p, float s) {
    float4 a = *(const float4*)p;
    float4 b = *(const float4*)(p + 4);
    i4 r;
    r[0] = pk(a.x * s, a.y * s); r[1] = pk(a.z * s, a.w * s);
    r[2] = pk(b.x * s, b.y * s); r[3] = pk(b.z * s, b.w * s);
    return r;
}

// quad-lane exchange via DPP (VALU pipe). Control must be constant -> template.
template <int CTRL>
__device__ __forceinline__ float qperm(float x) {
    return __int_as_float(
        __builtin_amdgcn_mov_dpp(__float_as_int(x), CTRL, 0xF, 0xF, true));
}
#define qx1(x)  qperm<0xB1>(x) /* quad_perm [1,0,3,2] lane^1 */
#define qx2(x)  qperm<0x4E>(x) /* quad_perm [2,3,0,1] lane^2 */

// ---------------------------------------------------------------------------
// Phase A (tiled): xg[s][j*4+g] = (dot(x[s], W_ih[g*128+j]) + b) * LOG2E
// ---------------------------------------------------------------------------
__global__ __launch_bounds__(256) void xg_gemm_t(
    const float* __restrict__ x, const float* __restrict__ Wih,
    const float* __restrict__ bih, const float* __restrict__ bhh,
    float* __restrict__ xg)
{
    __shared__ __align__(16) float sx[16 * IN_DIM]; // 4 KB
    const int t  = threadIdx.x;
    const int s0 = blockIdx.x * 16;

    *(float4*)&sx[t * 4] = *(const float4*)(x + (size_t)s0 * IN_DIM + t * 4);
    __syncthreads();

    const int r0 = (t & 3) * H + (t >> 2);
    const int r1 = r0 + 64;
    const float* w0p = Wih + (size_t)r0 * IN_DIM;
    const float* w1p = Wih + (size_t)r1 * IN_DIM;

    float acc0[16], acc1[16];
#pragma unroll
    for (int s = 0; s < 16; ++s) { acc0[s] = 0.f; acc1[s] = 0.f; }

#pragma unroll
    for (int k = 0; k < IN_DIM; k += 4) {
        float4 w0 = *(const float4*)(w0p + k);
        float4 w1 = *(const float4*)(w1p + k);
#pragma unroll
        for (int s = 0; s < 16; ++s) {
            float4 xv = *(const float4*)&sx[s * IN_DIM + k];
            acc0[s] += w0.x * xv.x + w0.y * xv.y + w0.z * xv.z + w0.w * xv.w;
            acc1[s] += w1.x * xv.x + w1.y * xv.y + w1.z * xv.z + w1.w * xv.w;
        }
    }

    const float b0 = bih[r0] + bhh[r0];
    const float b1 = bih[r1] + bhh[r1];
#pragma unroll
    for (int s = 0; s < 16; ++s) {
        xg[(size_t)(s0 + s) * G4 + t]       = (acc0[s] + b0) * LOG2E;
        xg[(size_t)(s0 + s) * G4 + t + 256] = (acc1[s] + b1) * LOG2E;
    }
}

// ---------------------------------------------------------------------------
// Phase B: persistent 256-thread (4-wave, 1/SIMD) scan.
// R11 dot structure (two 16-deep fdot2 chains/gate — R12's 4-chain split
// REGRESSED, falsifying the latency-8 theory). New this round: lane-pair
// sigma-split. Each cell is finalized redundantly by 2 lanes (ql, ql^2);
// lanes ql<2 evaluate sigma for {i,f}, lanes ql>=2 for {g,o}, in the same
// instruction slots (operand selects) with a PAIRED rcp; one qx2 exchange
// distributes all 4 gates. Trans ops/step: 10 -> 5 (quarter-rate pipe:
// 160 -> 80 issue cyc). Inputs clamped +-40 so pa*pb cannot overflow.
// ---------------------------------------------------------------------------
__attribute__((amdgpu_waves_per_eu(1, 1)))
__global__ __launch_bounds__(256) void lstm_scan(
    const float* __restrict__ Whh, const float* __restrict__ Wlin,
    const float* __restrict__ blin, const float* __restrict__ xg,
    float* __restrict__ out)
{
    __shared__ __align__(16) half_t shbuf[2][H]; // 512 B double-buffered h
    const int tid = threadIdx.x;
    const int ql  = tid & 3;
    const int j0  = (tid >> 2) * 2;
    const int c0  = ql * 32;
    const int jF  = j0 + (ql & 1);   // the cell this lane finalizes
    const bool hi = (ql & 2) != 0;   // sigma role: lo={i,f}, hi={g,o}

    // ---- weights: 8 rows x 32 cols, packed f16, pre-scaled by LOG2E ----
#define LOADW(P, ROW)                                                     \
    i4 P##0 = cvt8i_s(Whh + (size_t)(ROW) * H + c0 + 0,  LOG2E),          \
       P##1 = cvt8i_s(Whh + (size_t)(ROW) * H + c0 + 8,  LOG2E),          \
       P##2 = cvt8i_s(Whh + (size_t)(ROW) * H + c0 + 16, LOG2E),          \
       P##3 = cvt8i_s(Whh + (size_t)(ROW) * H + c0 + 24, LOG2E);
    LOADW(wi0, j0)           LOADW(wi1, j0 + 1)
    LOADW(wf0, 128 + j0)     LOADW(wf1, 129 + j0)
    LOADW(wg0, 256 + j0)     LOADW(wg1, 257 + j0)
    LOADW(wo0, 384 + j0)     LOADW(wo1, 385 + j0)
#undef LOADW
#define PIN(A, B, C, D) asm volatile("" : "+v"(A), "+v"(B), "+v"(C), "+v"(D))
    PIN(wi00, wi01, wi02, wi03); PIN(wi10, wi11, wi12, wi13);
    PIN(wf00, wf01, wf02, wf03); PIN(wf10, wf11, wf12, wf13);
    PIN(wg00, wg01, wg02, wg03); PIN(wg10, wg11, wg12, wg13);
    PIN(wo00, wo01, wo02, wo03); PIN(wo10, wo11, wo12, wo13);
#undef PIN

    const float* xgq = xg + (size_t)jF * 4; // [s][j][gate] float4 for my cell
    float c = 0.f;
    const float K2 = 2.f * LOG2E;

    // xg ring: depth-2 prefetch
    float4 xg_c = *(const float4*)(xgq + (size_t)0 * G4);
    float4 xg_n = *(const float4*)(xgq + (size_t)1 * G4);

    if (tid < H) shbuf[0][tid] = (half_t)0.f;
    __syncthreads();

#define DOT8(ACC, WV, HV)                                                 \
    ACC = dot2i(WV[0], HV[0], ACC);                                       \
    ACC = dot2i(WV[1], HV[1], ACC);                                       \
    ACC = dot2i(WV[2], HV[2], ACC);                                       \
    ACC = dot2i(WV[3], HV[3], ACC);
#define DROW(ACC, P)                                                      \
    DOT8(ACC, P##0, h0) DOT8(ACC, P##1, h1)                               \
    DOT8(ACC, P##2, h2) DOT8(ACC, P##3, h3)
// fused select + 2-hop butterfly: S = full row-sum for cell jF of this gate
#define GRED(S, A0, A1)                                                   \
    float S;                                                              \
    {   S        = (ql & 1) ? (A1) : (A0);                                \
        float b_ = (ql & 1) ? (A0) : (A1);                                \
        S += qx1(b_);                                                     \
        S += qx2(S); }

#define STEP(RB, WB, T)                                                   \
    {                                                                     \
        const i4* hp = (const i4*)&shbuf[RB][c0];                         \
        i4 h0 = hp[0], h1 = hp[1], h2 = hp[2], h3 = hp[3];                \
        int tp = (T) + 2; if (tp > SEQ - 1) tp = SEQ - 1;                 \
        float4 xg_p = *(const float4*)(xgq + (size_t)tp * G4);            \
        float ag0 = 0.f, ag1 = 0.f, ai0 = 0.f, ai1 = 0.f;                 \
        float af0 = 0.f, af1 = 0.f, ao0 = 0.f, ao1 = 0.f;                 \
        DROW(ag0, wg0) DROW(ag1, wg1)                                     \
        GRED(sg, ag0, ag1)                                                \
        DROW(ai0, wi0) DROW(ai1, wi1)                                     \
        GRED(si, ai0, ai1)                                                \
        DROW(af0, wf0) DROW(af1, wf1)                                     \
        GRED(sf, af0, af1)                                                \
        DROW(ao0, wo0) DROW(ao1, wo1)                                     \
        GRED(so, ao0, ao1)                                                \
        /* lane-pair sigma-split: lo lanes do {i,f}, hi lanes do {2g,o} */\
        float ug = sg + xg_c.z;                                           \
        float ua = hi ? ug + ug        : si + xg_c.x;                     \
        float ub = hi ? so + xg_c.w    : sf + xg_c.y;                     \
        ua = fminf(fmaxf(ua, -40.f), 40.f);                               \
        ub = fminf(fmaxf(ub, -40.f), 40.f);                               \
        float ea = exp2_fast(-ua), eb = exp2_fast(-ub);                   \
        float pa = 1.f + ea, pb = 1.f + eb;                               \
        float r_ = fast_rcp(pa * pb);                                     \
        float va = pb * r_;  /* sigma(ua) */                              \
        float vb = pa * r_;  /* sigma(ub) */                              \
        float wa = qx2(va), wb = qx2(vb); /* partner's pair */            \
        float gi  = hi ? wa : va;                                         \
        float gf  = hi ? wb : vb;                                         \
        float s2g = hi ? va : wa;                                         \
        float go  = hi ? vb : wb;                                         \
        float gg  = s2g + s2g - 1.f;   /* tanh = 2*sig(2x)-1 */           \
        c = gf * c + gi * gg;                                             \
        float uc = c * K2;                                                \
        uc = fminf(fmaxf(uc, -40.f), 40.f);                               \
        float sc = sig2(uc);                                              \
        float th = sc + sc - 1.f;                                         \
        float hh = go * th;                                               \
        if (ql < 2) shbuf[WB][jF] = (half_t)hh;                           \
        asm volatile("s_waitcnt lgkmcnt(0)" ::: "memory");                \
        __builtin_amdgcn_s_barrier();                                     \
        __builtin_amdgcn_sched_barrier(0);                                \
        xg_c = xg_n; xg_n = xg_p;                                         \
    }

    for (int t = 0; t < SEQ; t += 2) {
        STEP(0, 1, t)
        STEP(1, 0, t + 1)
    }
#undef STEP
#undef GRED
#undef DROW
#undef DOT8

    // h(SEQ) in shbuf[0]; one wave reduces the linear head.
    if (tid < 64) {
        float p = (float)shbuf[0][tid] * Wlin[tid] +
                  (float)shbuf[0][tid + 64] * Wlin[tid + 64];
#pragma unroll
        for (int off = 32; off > 0; off >>= 1) p += __shfl_down(p, off);
        if (tid == 0) out[0] = sigmoid_f(p + blin[0]);
    }
}

// ---------------------------------------------------------------------------
// Fallback (ws too small): self-contained, known-correct (R2 structure).
// ---------------------------------------------------------------------------
__global__ __launch_bounds__(512, 2) void lstm_scan_fb(
    const float* __restrict__ x, const float* __restrict__ Wih,
    const float* __restrict__ Whh, const float* __restrict__ bih,
    const float* __restrict__ bhh, const float* __restrict__ Wlin,
    const float* __restrict__ blin, float* __restrict__ out)
{
    __shared__ __align__(16) half_t sh_h[H];
    __shared__ __align__(16) float  sh_g[G4];
    const int row = threadIdx.x;
    const float* wrow = Whh + (long long)row * H;

    i4 w0 = cvt8i_s(wrow + 0, 1.f),   w1 = cvt8i_s(wrow + 8, 1.f);
    i4 w2 = cvt8i_s(wrow + 16, 1.f),  w3 = cvt8i_s(wrow + 24, 1.f);
    i4 w4 = cvt8i_s(wrow + 32, 1.f),  w5 = cvt8i_s(wrow + 40, 1.f);
    i4 w6 = cvt8i_s(wrow + 48, 1.f),  w7 = cvt8i_s(wrow + 56, 1.f);
    i4 w8 = cvt8i_s(wrow + 64, 1.f),  w9 = cvt8i_s(wrow + 72, 1.f);
    i4 w10 = cvt8i_s(wrow + 80, 1.f), w11 = cvt8i_s(wrow + 88, 1.f);
    i4 w12 = cvt8i_s(wrow + 96, 1.f), w13 = cvt8i_s(wrow + 104, 1.f);
    i4 w14 = cvt8i_s(wrow + 112, 1.f), w15 = cvt8i_s(wrow + 120, 1.f);

    const float bsum = bih[row] + bhh[row];
    float c = 0.f;
    if (row < H) sh_h[row] = (half_t)0.f;

    float xg_cur;
    {
        float a = bsum;
        const float* wir = Wih + (long long)row * IN_DIM;
#pragma unroll
        for (int k = 0; k < IN_DIM; k += 4) {
            float4 iv = *(const float4*)(x + k);
            float4 wv = *(const float4*)(wir + k);
            a += wv.x * iv.x + wv.y * iv.y + wv.z * iv.z + wv.w * iv.w;
        }
        xg_cur = a;
    }
    const bool is_g = (row >= 2 * H) && (row < 3 * H);
    __syncthreads();

    const i4* hch = (const i4*)sh_h;

    for (int t = 0; t < SEQ; ++t) {
        float xg_nxt = 0.f;
        if (t + 1 < SEQ) {
            const float* xr = x + (size_t)(t + 1) * IN_DIM;
            const float* wir = Wih + (long long)row * IN_DIM;
            float a = bsum;
#pragma unroll
            for (int k = 0; k < IN_DIM; k += 4) {
                float4 iv = *(const float4*)(xr + k);
                float4 wv = *(const float4*)(wir + k);
                a += wv.x * iv.x + wv.y * iv.y + wv.z * iv.z + wv.w * iv.w;
            }
            xg_nxt = a;
        }
        float a0 = 0.f, a1 = 0.f, a2 = 0.f, a3 = 0.f;
#define DOTC(WV, CI)                                                     \
        {   i4 hv = hch[CI];                                             \
            a0 = dot2i(WV[0], hv[0], a0);                                \
            a1 = dot2i(WV[1], hv[1], a1);                                \
            a2 = dot2i(WV[2], hv[2], a2);                                \
            a3 = dot2i(WV[3], hv[3], a3); }
        DOTC(w0, 0)  DOTC(w1, 1)  DOTC(w2, 2)   DOTC(w3, 3)
        DOTC(w4, 4)  DOTC(w5, 5)  DOTC(w6, 6)   DOTC(w7, 7)
        DOTC(w8, 8)  DOTC(w9, 9)  DOTC(w10, 10) DOTC(w11, 11)
        DOTC(w12, 12) DOTC(w13, 13) DOTC(w14, 14) DOTC(w15, 15)
#undef DOTC
        float pre = xg_cur + ((a0 + a1) + (a2 + a3));
        float gv;
        if (is_g) {
            float s = sigmoid_f(pre + pre);
            gv = s + s - 1.f;
        } else {
            gv = sigmoid_f(pre);
        }
        sh_g[row] = gv;
        __syncthreads();
        if (row >= 3 * H) {
            int jj = row - 3 * H;
            float ig = sh_g[jj];
            float fg = sh_g[H + jj];
            float gg = sh_g[2 * H + jj];
            c = fg * c + ig * gg;
            float s = sigmoid_f(c + c);
            sh_h[jj] = (half_t)(gv * (s + s - 1.f));
        }
        __syncthreads();
        xg_cur = xg_nxt;
    }

    if (row < 64) {
        float p = (float)sh_h[row] * Wlin[row] +
                  (float)sh_h[row + 64] * Wlin[row + 64];
#pragma unroll
        for (int off = 32; off > 0; off >>= 1) p += __shfl_down(p, off);
        if (row == 0) out[0] = sigmoid_f(p + blin[0]);
    }
}

extern "C" void kernel_launch(void* const* d_in, const int* in_sizes, int n_in,
                              void* d_out, int out_size, void* d_ws, size_t ws_size,
                              hipStream_t stream)
{
    const float* x    = (const float*)d_in[0];
    const float* Wih  = (const float*)d_in[1];
    const float* Whh  = (const float*)d_in[2];
    const float* bih  = (const float*)d_in[3];
    const float* bhh  = (const float*)d_in[4];
    const float* Wlin = (const float*)d_in[5];
    const float* blin = (const float*)d_in[6];
    float* out = (float*)d_out;

    const size_t need = (size_t)SEQ * G4 * sizeof(float); // 128 MB
    if (ws_size >= need) {
        float* xg = (float*)d_ws;
        xg_gemm_t<<<SEQ / 16, 256, 0, stream>>>(x, Wih, bih, bhh, xg);
        lstm_scan<<<1, 256, 0, stream>>>(Whh, Wlin, blin, xg, out);
    } else {
        lstm_scan_fb<<<1, 512, 0, stream>>>(x, Wih, Whh, bih, bhh, Wlin,
                                            blin, out);
    }
}

// Round 14
// 30827.161 us; speedup vs baseline: 1.0407x; 1.0407x over previous
//
#include <hip/hip_runtime.h>

#define SEQ 65536
#define IN_DIM 64
#define H 128
#define G4 512
#define LOG2E 1.4426950408889634f

typedef _Float16 half_t;
typedef half_t half2_t __attribute__((ext_vector_type(2)));
typedef int    i4     __attribute__((ext_vector_type(4)));

__device__ __forceinline__ float fast_rcp(float x) { return __builtin_amdgcn_rcpf(x); }

__device__ __forceinline__ float exp2_fast(float x) {
#if __has_builtin(__builtin_amdgcn_exp2f)
    return __builtin_amdgcn_exp2f(x);
#else
    return exp2f(x);
#endif
}

// sigmoid of (u / log2e): u PRE-SCALED by log2e -> rcp(1+exp2(-u)).
// Overflow-safe: exp2(+inf)->inf->rcp->0; exp2(-inf)->0->rcp(1)->1.
__device__ __forceinline__ float sig2(float u) {
    return fast_rcp(1.f + exp2_fast(-u));
}

__device__ __forceinline__ float sigmoid_f(float x) {
    return sig2(x * LOG2E);
}

#if __has_builtin(__builtin_amdgcn_fdot2)
__device__ __forceinline__ float dot2i(int w, int h, float acc) {
    return __builtin_amdgcn_fdot2(__builtin_bit_cast(half2_t, w),
                                  __builtin_bit_cast(half2_t, h), acc, false);
}
#else
__device__ __forceinline__ float dot2i(int w, int h, float acc) {
    half2_t a = __builtin_bit_cast(half2_t, w);
    half2_t b = __builtin_bit_cast(half2_t, h);
    return acc + (float)a[0] * (float)b[0] + (float)a[1] * (float)b[1];
}
#endif

// two f32 -> one VGPR of packed 2xf16 (v_cvt_pkrtz_f16_f32)
__device__ __forceinline__ int pk(float a, float b) {
    return __builtin_bit_cast(int, __builtin_amdgcn_cvt_pkrtz(a, b));
}

// 8 fp32 -> int4 of packed half2s, scaled by s
__device__ __forceinline__ i4 cvt8i_s(const float* p, float s) {
    float4 a = *(const float4*)p;
    float4 b = *(const float4*)(p + 4);
    i4 r;
    r[0] = pk(a.x * s, a.y * s); r[1] = pk(a.z * s, a.w * s);
    r[2] = pk(b.x * s, b.y * s); r[3] = pk(b.z * s, b.w * s);
    return r;
}

// quad-lane exchange via DPP (VALU pipe). Control must be constant -> template.
template <int CTRL>
__device__ __forceinline__ float qperm(float x) {
    return __int_as_float(
        __builtin_amdgcn_mov_dpp(__float_as_int(x), CTRL, 0xF, 0xF, true));
}
#define qx1(x)  qperm<0xB1>(x) /* quad_perm [1,0,3,2] lane^1 */
#define qx2(x)  qperm<0x4E>(x) /* quad_perm [2,3,0,1] lane^2 */

// ---------------------------------------------------------------------------
// Phase A (tiled): xg[s][j*4+g] = (dot(x[s], W_ih[g*128+j]) + b) * LOG2E
// ---------------------------------------------------------------------------
__global__ __launch_bounds__(256) void xg_gemm_t(
    const float* __restrict__ x, const float* __restrict__ Wih,
    const float* __restrict__ bih, const float* __restrict__ bhh,
    float* __restrict__ xg)
{
    __shared__ __align__(16) float sx[16 * IN_DIM]; // 4 KB
    const int t  = threadIdx.x;
    const int s0 = blockIdx.x * 16;

    *(float4*)&sx[t * 4] = *(const float4*)(x + (size_t)s0 * IN_DIM + t * 4);
    __syncthreads();

    const int r0 = (t & 3) * H + (t >> 2);
    const int r1 = r0 + 64;
    const float* w0p = Wih + (size_t)r0 * IN_DIM;
    const float* w1p = Wih + (size_t)r1 * IN_DIM;

    float acc0[16], acc1[16];
#pragma unroll
    for (int s = 0; s < 16; ++s) { acc0[s] = 0.f; acc1[s] = 0.f; }

#pragma unroll
    for (int k = 0; k < IN_DIM; k += 4) {
        float4 w0 = *(const float4*)(w0p + k);
        float4 w1 = *(const float4*)(w1p + k);
#pragma unroll
        for (int s = 0; s < 16; ++s) {
            float4 xv = *(const float4*)&sx[s * IN_DIM + k];
            acc0[s] += w0.x * xv.x + w0.y * xv.y + w0.z * xv.z + w0.w * xv.w;
            acc1[s] += w1.x * xv.x + w1.y * xv.y + w1.z * xv.z + w1.w * xv.w;
        }
    }

    const float b0 = bih[r0] + bhh[r0];
    const float b1 = bih[r1] + bhh[r1];
#pragma unroll
    for (int s = 0; s < 16; ++s) {
        xg[(size_t)(s0 + s) * G4 + t]       = (acc0[s] + b0) * LOG2E;
        xg[(size_t)(s0 + s) * G4 + t + 256] = (acc1[s] + b1) * LOG2E;
    }
}

// ---------------------------------------------------------------------------
// Phase B: persistent 256-thread (4-wave, 1/SIMD) scan.
// REVERT to the measured-best R11 structure (1063 cyc/step): per-gate
// {2x16-deep fdot2 chains -> fused-select butterfly GRED -> sigma}, order
// g->i->f->o so each sigma hides under the next gate's dots (R13's sigma
// batching put all trans on the critical path: VALUBusy fell, time rose).
// Three pure issue shaves vs R11:
//  - zero-mov xg ring: two named regs (xgA/xgB) alternate with the 2x
//    unrolled loop; reload in place right after last use (-8 v_mov/step).
//  - no sched_barrier(0) (lgkmcnt asm + s_barrier already order LDS).
//  - direct ds_write_b16 (drops qx1+pk from the tail; still 1 DS instr).
// ---------------------------------------------------------------------------
__attribute__((amdgpu_waves_per_eu(1, 1)))
__global__ __launch_bounds__(256) void lstm_scan(
    const float* __restrict__ Whh, const float* __restrict__ Wlin,
    const float* __restrict__ blin, const float* __restrict__ xg,
    float* __restrict__ out)
{
    __shared__ __align__(16) half_t shbuf[2][H]; // 512 B double-buffered h
    const int tid = threadIdx.x;
    const int ql  = tid & 3;
    const int j0  = (tid >> 2) * 2;
    const int c0  = ql * 32;
    const int jF  = j0 + (ql & 1);   // the cell this lane finalizes

    // ---- weights: 8 rows x 32 cols, packed f16, pre-scaled by LOG2E ----
#define LOADW(P, ROW)                                                     \
    i4 P##0 = cvt8i_s(Whh + (size_t)(ROW) * H + c0 + 0,  LOG2E),          \
       P##1 = cvt8i_s(Whh + (size_t)(ROW) * H + c0 + 8,  LOG2E),          \
       P##2 = cvt8i_s(Whh + (size_t)(ROW) * H + c0 + 16, LOG2E),          \
       P##3 = cvt8i_s(Whh + (size_t)(ROW) * H + c0 + 24, LOG2E);
    LOADW(wi0, j0)           LOADW(wi1, j0 + 1)
    LOADW(wf0, 128 + j0)     LOADW(wf1, 129 + j0)
    LOADW(wg0, 256 + j0)     LOADW(wg1, 257 + j0)
    LOADW(wo0, 384 + j0)     LOADW(wo1, 385 + j0)
#undef LOADW
#define PIN(A, B, C, D) asm volatile("" : "+v"(A), "+v"(B), "+v"(C), "+v"(D))
    PIN(wi00, wi01, wi02, wi03); PIN(wi10, wi11, wi12, wi13);
    PIN(wf00, wf01, wf02, wf03); PIN(wf10, wf11, wf12, wf13);
    PIN(wg00, wg01, wg02, wg03); PIN(wg10, wg11, wg12, wg13);
    PIN(wo00, wo01, wo02, wo03); PIN(wo10, wo11, wo12, wo13);
#undef PIN

    const float* xgq = xg + (size_t)jF * 4; // [s][j][gate] float4 for my cell
    float c = 0.f;
    const float K2 = 2.f * LOG2E;

    // xg ring: depth-2, zero-mov (xgA = even steps, xgB = odd steps)
    float4 xgA = *(const float4*)(xgq + (size_t)0 * G4);
    float4 xgB = *(const float4*)(xgq + (size_t)1 * G4);

    if (tid < H) shbuf[0][tid] = (half_t)0.f;
    __syncthreads();

#define DOT8(ACC, WV, HV)                                                 \
    ACC = dot2i(WV[0], HV[0], ACC);                                       \
    ACC = dot2i(WV[1], HV[1], ACC);                                       \
    ACC = dot2i(WV[2], HV[2], ACC);                                       \
    ACC = dot2i(WV[3], HV[3], ACC);
#define DROW(ACC, P)                                                      \
    DOT8(ACC, P##0, h0) DOT8(ACC, P##1, h1)                               \
    DOT8(ACC, P##2, h2) DOT8(ACC, P##3, h3)
// fused select + 2-hop butterfly: S = full row-sum for cell jF of this gate
#define GRED(S, A0, A1)                                                   \
    float S;                                                              \
    {   S        = (ql & 1) ? (A1) : (A0);                                \
        float b_ = (ql & 1) ? (A0) : (A1);                                \
        S += qx1(b_);                                                     \
        S += qx2(S); }

#define STEP(RB, WB, T, XGC)                                              \
    {                                                                     \
        const i4* hp = (const i4*)&shbuf[RB][c0];                         \
        i4 h0 = hp[0], h1 = hp[1], h2 = hp[2], h3 = hp[3];                \
        float ag0 = 0.f, ag1 = 0.f, ai0 = 0.f, ai1 = 0.f;                 \
        float af0 = 0.f, af1 = 0.f, ao0 = 0.f, ao1 = 0.f;                 \
        /* g first: its sigma is the longest pole (feeds c) */            \
        DROW(ag0, wg0) DROW(ag1, wg1)                                     \
        GRED(sg, ag0, ag1)                                                \
        float ug  = sg + XGC.z;                                           \
        float s2g = sig2(ug + ug);                                        \
        float gg  = s2g + s2g - 1.f;   /* tanh = 2*sig(2x)-1 */           \
        DROW(ai0, wi0) DROW(ai1, wi1)                                     \
        GRED(si, ai0, ai1)                                                \
        float gi = sig2(si + XGC.x);                                      \
        DROW(af0, wf0) DROW(af1, wf1)                                     \
        GRED(sf, af0, af1)                                                \
        float gf = sig2(sf + XGC.y);                                      \
        DROW(ao0, wo0) DROW(ao1, wo1)                                     \
        GRED(so, ao0, ao1)                                                \
        float go = sig2(so + XGC.w); /* parallel with c-chain below */    \
        /* XGC fully consumed: reload in place for step T+2 (rides */     \
        /* across two barriers; per-register vmcnt waits only at use) */  \
        {   int tp = (T) + 2; if (tp > SEQ - 1) tp = SEQ - 1;             \
            XGC = *(const float4*)(xgq + (size_t)tp * G4); }              \
        c = gf * c + gi * gg;                                             \
        float sc = sig2(c * K2);                                          \
        float th = sc + sc - 1.f;                                         \
        float hh = go * th;                                               \
        if (ql < 2) shbuf[WB][jF] = (half_t)hh;                           \
        asm volatile("s_waitcnt lgkmcnt(0)" ::: "memory");                \
        __builtin_amdgcn_s_barrier();                                     \
    }

    for (int t = 0; t < SEQ; t += 2) {
        STEP(0, 1, t, xgA)
        STEP(1, 0, t + 1, xgB)
    }
#undef STEP
#undef GRED
#undef DROW
#undef DOT8

    // h(SEQ) in shbuf[0]; one wave reduces the linear head.
    if (tid < 64) {
        float p = (float)shbuf[0][tid] * Wlin[tid] +
                  (float)shbuf[0][tid + 64] * Wlin[tid + 64];
#pragma unroll
        for (int off = 32; off > 0; off >>= 1) p += __shfl_down(p, off);
        if (tid == 0) out[0] = sigmoid_f(p + blin[0]);
    }
}

// ---------------------------------------------------------------------------
// Fallback (ws too small): self-contained, known-correct (R2 structure).
// ---------------------------------------------------------------------------
__global__ __launch_bounds__(512, 2) void lstm_scan_fb(
    const float* __restrict__ x, const float* __restrict__ Wih,
    const float* __restrict__ Whh, const float* __restrict__ bih,
    const float* __restrict__ bhh, const float* __restrict__ Wlin,
    const float* __restrict__ blin, float* __restrict__ out)
{
    __shared__ __align__(16) half_t sh_h[H];
    __shared__ __align__(16) float  sh_g[G4];
    const int row = threadIdx.x;
    const float* wrow = Whh + (long long)row * H;

    i4 w0 = cvt8i_s(wrow + 0, 1.f),   w1 = cvt8i_s(wrow + 8, 1.f);
    i4 w2 = cvt8i_s(wrow + 16, 1.f),  w3 = cvt8i_s(wrow + 24, 1.f);
    i4 w4 = cvt8i_s(wrow + 32, 1.f),  w5 = cvt8i_s(wrow + 40, 1.f);
    i4 w6 = cvt8i_s(wrow + 48, 1.f),  w7 = cvt8i_s(wrow + 56, 1.f);
    i4 w8 = cvt8i_s(wrow + 64, 1.f),  w9 = cvt8i_s(wrow + 72, 1.f);
    i4 w10 = cvt8i_s(wrow + 80, 1.f), w11 = cvt8i_s(wrow + 88, 1.f);
    i4 w12 = cvt8i_s(wrow + 96, 1.f), w13 = cvt8i_s(wrow + 104, 1.f);
    i4 w14 = cvt8i_s(wrow + 112, 1.f), w15 = cvt8i_s(wrow + 120, 1.f);

    const float bsum = bih[row] + bhh[row];
    float c = 0.f;
    if (row < H) sh_h[row] = (half_t)0.f;

    float xg_cur;
    {
        float a = bsum;
        const float* wir = Wih + (long long)row * IN_DIM;
#pragma unroll
        for (int k = 0; k < IN_DIM; k += 4) {
            float4 iv = *(const float4*)(x + k);
            float4 wv = *(const float4*)(wir + k);
            a += wv.x * iv.x + wv.y * iv.y + wv.z * iv.z + wv.w * iv.w;
        }
        xg_cur = a;
    }
    const bool is_g = (row >= 2 * H) && (row < 3 * H);
    __syncthreads();

    const i4* hch = (const i4*)sh_h;

    for (int t = 0; t < SEQ; ++t) {
        float xg_nxt = 0.f;
        if (t + 1 < SEQ) {
            const float* xr = x + (size_t)(t + 1) * IN_DIM;
            const float* wir = Wih + (long long)row * IN_DIM;
            float a = bsum;
#pragma unroll
            for (int k = 0; k < IN_DIM; k += 4) {
                float4 iv = *(const float4*)(xr + k);
                float4 wv = *(const float4*)(wir + k);
                a += wv.x * iv.x + wv.y * iv.y + wv.z * iv.z + wv.w * iv.w;
            }
            xg_nxt = a;
        }
        float a0 = 0.f, a1 = 0.f, a2 = 0.f, a3 = 0.f;
#define DOTC(WV, CI)                                                     \
        {   i4 hv = hch[CI];                                             \
            a0 = dot2i(WV[0], hv[0], a0);                                \
            a1 = dot2i(WV[1], hv[1], a1);                                \
            a2 = dot2i(WV[2], hv[2], a2);                                \
            a3 = dot2i(WV[3], hv[3], a3); }
        DOTC(w0, 0)  DOTC(w1, 1)  DOTC(w2, 2)   DOTC(w3, 3)
        DOTC(w4, 4)  DOTC(w5, 5)  DOTC(w6, 6)   DOTC(w7, 7)
        DOTC(w8, 8)  DOTC(w9, 9)  DOTC(w10, 10) DOTC(w11, 11)
        DOTC(w12, 12) DOTC(w13, 13) DOTC(w14, 14) DOTC(w15, 15)
#undef DOTC
        float pre = xg_cur + ((a0 + a1) + (a2 + a3));
        float gv;
        if (is_g) {
            float s = sigmoid_f(pre + pre);
            gv = s + s - 1.f;
        } else {
            gv = sigmoid_f(pre);
        }
        sh_g[row] = gv;
        __syncthreads();
        if (row >= 3 * H) {
            int jj = row - 3 * H;
            float ig = sh_g[jj];
            float fg = sh_g[H + jj];
            float gg = sh_g[2 * H + jj];
            c = fg * c + ig * gg;
            float s = sigmoid_f(c + c);
            sh_h[jj] = (half_t)(gv * (s + s - 1.f));
        }
        __syncthreads();
        xg_cur = xg_nxt;
    }

    if (row < 64) {
        float p = (float)sh_h[row] * Wlin[row] +
                  (float)sh_h[row + 64] * Wlin[row + 64];
#pragma unroll
        for (int off = 32; off > 0; off >>= 1) p += __shfl_down(p, off);
        if (row == 0) out[0] = sigmoid_f(p + blin[0]);
    }
}

extern "C" void kernel_launch(void* const* d_in, const int* in_sizes, int n_in,
                              void* d_out, int out_size, void* d_ws, size_t ws_size,
                              hipStream_t stream)
{
    const float* x    = (const float*)d_in[0];
    const float* Wih  = (const float*)d_in[1];
    const float* Whh  = (const float*)d_in[2];
    const float* bih  = (const float*)d_in[3];
    const float* bhh  = (const float*)d_in[4];
    const float* Wlin = (const float*)d_in[5];
    const float* blin = (const float*)d_in[6];
    float* out = (float*)d_out;

    const size_t need = (size_t)SEQ * G4 * sizeof(float); // 128 MB
    if (ws_size >= need) {
        float* xg = (float*)d_ws;
        xg_gemm_t<<<SEQ / 16, 256, 0, stream>>>(x, Wih, bih, bhh, xg);
        lstm_scan<<<1, 256, 0, stream>>>(Whh, Wlin, blin, xg, out);
    } else {
        lstm_scan_fb<<<1, 512, 0, stream>>>(x, Wih, Whh, bih, bhh, Wlin,
                                            blin, out);
    }
}

// Round 15
// 29031.290 us; speedup vs baseline: 1.1051x; 1.0619x over previous
//
#include <hip/hip_runtime.h>

#define SEQ 65536
#define IN_DIM 64
#define H 128
#define G4 512
#define LOG2E 1.4426950408889634f

typedef _Float16 half_t;
typedef half_t half2_t __attribute__((ext_vector_type(2)));
typedef int    i4     __attribute__((ext_vector_type(4)));

__device__ __forceinline__ float fast_rcp(float x) { return __builtin_amdgcn_rcpf(x); }

__device__ __forceinline__ float exp2_fast(float x) {
#if __has_builtin(__builtin_amdgcn_exp2f)
    return __builtin_amdgcn_exp2f(x);
#else
    return exp2f(x);
#endif
}

// sigmoid of (u / log2e): u PRE-SCALED by log2e -> rcp(1+exp2(-u)).
// Overflow-safe: exp2(+inf)->inf->rcp->0; exp2(-inf)->0->rcp(1)->1.
__device__ __forceinline__ float sig2(float u) {
    return fast_rcp(1.f + exp2_fast(-u));
}

__device__ __forceinline__ float sigmoid_f(float x) {
    return sig2(x * LOG2E);
}

#if __has_builtin(__builtin_amdgcn_fdot2)
__device__ __forceinline__ float dot2i(int w, int h, float acc) {
    return __builtin_amdgcn_fdot2(__builtin_bit_cast(half2_t, w),
                                  __builtin_bit_cast(half2_t, h), acc, false);
}
#else
__device__ __forceinline__ float dot2i(int w, int h, float acc) {
    half2_t a = __builtin_bit_cast(half2_t, w);
    half2_t b = __builtin_bit_cast(half2_t, h);
    return acc + (float)a[0] * (float)b[0] + (float)a[1] * (float)b[1];
}
#endif

// two f32 -> one VGPR of packed 2xf16 (v_cvt_pkrtz_f16_f32)
__device__ __forceinline__ int pk(float a, float b) {
    return __builtin_bit_cast(int, __builtin_amdgcn_cvt_pkrtz(a, b));
}

// 8 fp32 -> int4 of packed half2s, scaled by s
__device__ __forceinline__ i4 cvt8i_s(const float* p, float s) {
    float4 a = *(const float4*)p;
    float4 b = *(const float4*)(p + 4);
    i4 r;
    r[0] = pk(a.x * s, a.y * s); r[1] = pk(a.z * s, a.w * s);
    r[2] = pk(b.x * s, b.y * s); r[3] = pk(b.z * s, b.w * s);
    return r;
}

// quad-lane exchange via DPP (VALU pipe). Control must be constant -> template.
template <int CTRL>
__device__ __forceinline__ float qperm(float x) {
    return __int_as_float(
        __builtin_amdgcn_mov_dpp(__float_as_int(x), CTRL, 0xF, 0xF, true));
}
#define qx1(x)  qperm<0xB1>(x) /* quad_perm [1,0,3,2] lane^1 */
#define qx2(x)  qperm<0x4E>(x) /* quad_perm [2,3,0,1] lane^2 */

// ---------------------------------------------------------------------------
// Phase A (tiled): xg[s][j*4+g] = (dot(x[s], W_ih[g*128+j]) + b) * LOG2E
// Block = 16 timesteps; x-tile in LDS; W rows in regs; ~16 MB total fetch.
// ---------------------------------------------------------------------------
__global__ __launch_bounds__(256) void xg_gemm_t(
    const float* __restrict__ x, const float* __restrict__ Wih,
    const float* __restrict__ bih, const float* __restrict__ bhh,
    float* __restrict__ xg)
{
    __shared__ __align__(16) float sx[16 * IN_DIM]; // 4 KB
    const int t  = threadIdx.x;
    const int s0 = blockIdx.x * 16;

    *(float4*)&sx[t * 4] = *(const float4*)(x + (size_t)s0 * IN_DIM + t * 4);
    __syncthreads();

    const int r0 = (t & 3) * H + (t >> 2);
    const int r1 = r0 + 64;
    const float* w0p = Wih + (size_t)r0 * IN_DIM;
    const float* w1p = Wih + (size_t)r1 * IN_DIM;

    float acc0[16], acc1[16];
#pragma unroll
    for (int s = 0; s < 16; ++s) { acc0[s] = 0.f; acc1[s] = 0.f; }

#pragma unroll
    for (int k = 0; k < IN_DIM; k += 4) {
        float4 w0 = *(const float4*)(w0p + k);
        float4 w1 = *(const float4*)(w1p + k);
#pragma unroll
        for (int s = 0; s < 16; ++s) {
            float4 xv = *(const float4*)&sx[s * IN_DIM + k];
            acc0[s] += w0.x * xv.x + w0.y * xv.y + w0.z * xv.z + w0.w * xv.w;
            acc1[s] += w1.x * xv.x + w1.y * xv.y + w1.z * xv.z + w1.w * xv.w;
        }
    }

    const float b0 = bih[r0] + bhh[r0];
    const float b1 = bih[r1] + bhh[r1];
#pragma unroll
    for (int s = 0; s < 16; ++s) {
        xg[(size_t)(s0 + s) * G4 + t]       = (acc0[s] + b0) * LOG2E;
        xg[(size_t)(s0 + s) * G4 + t + 256] = (acc1[s] + b1) * LOG2E;
    }
}

// ---------------------------------------------------------------------------
// Phase B: persistent 256-thread (4-wave, 1/SIMD) scan.
// EXACT restore of the round-11 measured-best configuration (29.08 ms,
// 1063 cyc/step). Every later variant regressed:
//   R12 4-chain ILP split:      +66 cyc (fdot2 dep latency is <=4, not 8)
//   R13 batched sigma pairs:    +110 cyc (trans moved onto critical path)
//   R14 late in-place xg reload + no sched_barrier: +64 cyc
// Structure: per gate {two 16-deep fdot2 chains -> fused-select butterfly
// GRED -> sigma}, order g->i->f->o so each sigma hides under the next
// gate's dots; mov-based depth-2 xg ring loaded at STEP START (max
// latency window, rides across barriers - no vmcnt(0) drain); packed
// qx1+pk h-write from lane 0; raw s_barrier with lgkmcnt-only drain +
// sched_barrier(0) pin.
// ---------------------------------------------------------------------------
__attribute__((amdgpu_waves_per_eu(1, 1)))
__global__ __launch_bounds__(256) void lstm_scan(
    const float* __restrict__ Whh, const float* __restrict__ Wlin,
    const float* __restrict__ blin, const float* __restrict__ xg,
    float* __restrict__ out)
{
    __shared__ __align__(16) half_t shbuf[2][H]; // 512 B double-buffered h
    const int tid = threadIdx.x;
    const int ql  = tid & 3;
    const int j0  = (tid >> 2) * 2;
    const int c0  = ql * 32;
    const int jF  = j0 + (ql & 1);   // the cell this lane finalizes

    // ---- weights: 8 rows x 32 cols, packed f16, pre-scaled by LOG2E ----
#define LOADW(P, ROW)                                                     \
    i4 P##0 = cvt8i_s(Whh + (size_t)(ROW) * H + c0 + 0,  LOG2E),          \
       P##1 = cvt8i_s(Whh + (size_t)(ROW) * H + c0 + 8,  LOG2E),          \
       P##2 = cvt8i_s(Whh + (size_t)(ROW) * H + c0 + 16, LOG2E),          \
       P##3 = cvt8i_s(Whh + (size_t)(ROW) * H + c0 + 24, LOG2E);
    LOADW(wi0, j0)           LOADW(wi1, j0 + 1)
    LOADW(wf0, 128 + j0)     LOADW(wf1, 129 + j0)
    LOADW(wg0, 256 + j0)     LOADW(wg1, 257 + j0)
    LOADW(wo0, 384 + j0)     LOADW(wo1, 385 + j0)
#undef LOADW
#define PIN(A, B, C, D) asm volatile("" : "+v"(A), "+v"(B), "+v"(C), "+v"(D))
    PIN(wi00, wi01, wi02, wi03); PIN(wi10, wi11, wi12, wi13);
    PIN(wf00, wf01, wf02, wf03); PIN(wf10, wf11, wf12, wf13);
    PIN(wg00, wg01, wg02, wg03); PIN(wg10, wg11, wg12, wg13);
    PIN(wo00, wo01, wo02, wo03); PIN(wo10, wo11, wo12, wo13);
#undef PIN

    const float* xgq = xg + (size_t)jF * 4; // [s][j][gate] float4 for my cell
    float c = 0.f;
    const float K2 = 2.f * LOG2E;

    // xg ring: depth-2 prefetch
    float4 xg_c = *(const float4*)(xgq + (size_t)0 * G4);
    float4 xg_n = *(const float4*)(xgq + (size_t)1 * G4);

    if (tid < H) shbuf[0][tid] = (half_t)0.f;
    __syncthreads();

#define DOT8(ACC, WV, HV)                                                 \
    ACC = dot2i(WV[0], HV[0], ACC);                                       \
    ACC = dot2i(WV[1], HV[1], ACC);                                       \
    ACC = dot2i(WV[2], HV[2], ACC);                                       \
    ACC = dot2i(WV[3], HV[3], ACC);
#define DROW(ACC, P)                                                      \
    DOT8(ACC, P##0, h0) DOT8(ACC, P##1, h1)                               \
    DOT8(ACC, P##2, h2) DOT8(ACC, P##3, h3)
// fused select + 2-hop butterfly: S = full row-sum for cell jF of this gate
#define GRED(S, A0, A1)                                                   \
    float S;                                                              \
    {   S        = (ql & 1) ? (A1) : (A0);                                \
        float b_ = (ql & 1) ? (A0) : (A1);                                \
        S += qx1(b_);                                                     \
        S += qx2(S); }

#define STEP(RB, WB, T)                                                   \
    {                                                                     \
        const i4* hp = (const i4*)&shbuf[RB][c0];                         \
        i4 h0 = hp[0], h1 = hp[1], h2 = hp[2], h3 = hp[3];                \
        int tp = (T) + 2; if (tp > SEQ - 1) tp = SEQ - 1;                 \
        float4 xg_p = *(const float4*)(xgq + (size_t)tp * G4);            \
        float ag0 = 0.f, ag1 = 0.f, ai0 = 0.f, ai1 = 0.f;                 \
        float af0 = 0.f, af1 = 0.f, ao0 = 0.f, ao1 = 0.f;                 \
        /* g first: its sigma is the longest pole (feeds c) */            \
        DROW(ag0, wg0) DROW(ag1, wg1)                                     \
        GRED(sg, ag0, ag1)                                                \
        float ug  = sg + xg_c.z;                                          \
        float s2g = sig2(ug + ug);                                        \
        float gg  = s2g + s2g - 1.f;   /* tanh = 2*sig(2x)-1 */           \
        DROW(ai0, wi0) DROW(ai1, wi1)                                     \
        GRED(si, ai0, ai1)                                                \
        float gi = sig2(si + xg_c.x);                                     \
        DROW(af0, wf0) DROW(af1, wf1)                                     \
        GRED(sf, af0, af1)                                                \
        float gf = sig2(sf + xg_c.y);                                     \
        DROW(ao0, wo0) DROW(ao1, wo1)                                     \
        GRED(so, ao0, ao1)                                                \
        float go = sig2(so + xg_c.w); /* parallel with c-chain below */   \
        c = gf * c + gi * gg;                                             \
        float sc = sig2(c * K2);                                          \
        float th = sc + sc - 1.f;                                         \
        float hh = go * th;                                               \
        float ho = qx1(hh);            /* partner cell's h */             \
        if (ql == 0)                                                      \
            ((int*)&shbuf[WB][0])[j0 >> 1] = pk(hh, ho);                  \
        asm volatile("s_waitcnt lgkmcnt(0)" ::: "memory");                \
        __builtin_amdgcn_s_barrier();                                     \
        __builtin_amdgcn_sched_barrier(0);                                \
        xg_c = xg_n; xg_n = xg_p;                                         \
    }

    for (int t = 0; t < SEQ; t += 2) {
        STEP(0, 1, t)
        STEP(1, 0, t + 1)
    }
#undef STEP
#undef GRED
#undef DROW
#undef DOT8

    // h(SEQ) in shbuf[0]; one wave reduces the linear head.
    if (tid < 64) {
        float p = (float)shbuf[0][tid] * Wlin[tid] +
                  (float)shbuf[0][tid + 64] * Wlin[tid + 64];
#pragma unroll
        for (int off = 32; off > 0; off >>= 1) p += __shfl_down(p, off);
        if (tid == 0) out[0] = sigmoid_f(p + blin[0]);
    }
}

// ---------------------------------------------------------------------------
// Fallback (ws too small): self-contained, known-correct (R2 structure).
// ---------------------------------------------------------------------------
__global__ __launch_bounds__(512, 2) void lstm_scan_fb(
    const float* __restrict__ x, const float* __restrict__ Wih,
    const float* __restrict__ Whh, const float* __restrict__ bih,
    const float* __restrict__ bhh, const float* __restrict__ Wlin,
    const float* __restrict__ blin, float* __restrict__ out)
{
    __shared__ __align__(16) half_t sh_h[H];
    __shared__ __align__(16) float  sh_g[G4];
    const int row = threadIdx.x;
    const float* wrow = Whh + (long long)row * H;

    i4 w0 = cvt8i_s(wrow + 0, 1.f),   w1 = cvt8i_s(wrow + 8, 1.f);
    i4 w2 = cvt8i_s(wrow + 16, 1.f),  w3 = cvt8i_s(wrow + 24, 1.f);
    i4 w4 = cvt8i_s(wrow + 32, 1.f),  w5 = cvt8i_s(wrow + 40, 1.f);
    i4 w6 = cvt8i_s(wrow + 48, 1.f),  w7 = cvt8i_s(wrow + 56, 1.f);
    i4 w8 = cvt8i_s(wrow + 64, 1.f),  w9 = cvt8i_s(wrow + 72, 1.f);
    i4 w10 = cvt8i_s(wrow + 80, 1.f), w11 = cvt8i_s(wrow + 88, 1.f);
    i4 w12 = cvt8i_s(wrow + 96, 1.f), w13 = cvt8i_s(wrow + 104, 1.f);
    i4 w14 = cvt8i_s(wrow + 112, 1.f), w15 = cvt8i_s(wrow + 120, 1.f);

    const float bsum = bih[row] + bhh[row];
    float c = 0.f;
    if (row < H) sh_h[row] = (half_t)0.f;

    float xg_cur;
    {
        float a = bsum;
        const float* wir = Wih + (long long)row * IN_DIM;
#pragma unroll
        for (int k = 0; k < IN_DIM; k += 4) {
            float4 iv = *(const float4*)(x + k);
            float4 wv = *(const float4*)(wir + k);
            a += wv.x * iv.x + wv.y * iv.y + wv.z * iv.z + wv.w * iv.w;
        }
        xg_cur = a;
    }
    const bool is_g = (row >= 2 * H) && (row < 3 * H);
    __syncthreads();

    const i4* hch = (const i4*)sh_h;

    for (int t = 0; t < SEQ; ++t) {
        float xg_nxt = 0.f;
        if (t + 1 < SEQ) {
            const float* xr = x + (size_t)(t + 1) * IN_DIM;
            const float* wir = Wih + (long long)row * IN_DIM;
            float a = bsum;
#pragma unroll
            for (int k = 0; k < IN_DIM; k += 4) {
                float4 iv = *(const float4*)(xr + k);
                float4 wv = *(const float4*)(wir + k);
                a += wv.x * iv.x + wv.y * iv.y + wv.z * iv.z + wv.w * iv.w;
            }
            xg_nxt = a;
        }
        float a0 = 0.f, a1 = 0.f, a2 = 0.f, a3 = 0.f;
#define DOTC(WV, CI)                                                     \
        {   i4 hv = hch[CI];                                             \
            a0 = dot2i(WV[0], hv[0], a0);                                \
            a1 = dot2i(WV[1], hv[1], a1);                                \
            a2 = dot2i(WV[2], hv[2], a2);                                \
            a3 = dot2i(WV[3], hv[3], a3); }
        DOTC(w0, 0)  DOTC(w1, 1)  DOTC(w2, 2)   DOTC(w3, 3)
        DOTC(w4, 4)  DOTC(w5, 5)  DOTC(w6, 6)   DOTC(w7, 7)
        DOTC(w8, 8)  DOTC(w9, 9)  DOTC(w10, 10) DOTC(w11, 11)
        DOTC(w12, 12) DOTC(w13, 13) DOTC(w14, 14) DOTC(w15, 15)
#undef DOTC
        float pre = xg_cur + ((a0 + a1) + (a2 + a3));
        float gv;
        if (is_g) {
            float s = sigmoid_f(pre + pre);
            gv = s + s - 1.f;
        } else {
            gv = sigmoid_f(pre);
        }
        sh_g[row] = gv;
        __syncthreads();
        if (row >= 3 * H) {
            int jj = row - 3 * H;
            float ig = sh_g[jj];
            float fg = sh_g[H + jj];
            float gg = sh_g[2 * H + jj];
            c = fg * c + ig * gg;
            float s = sigmoid_f(c + c);
            sh_h[jj] = (half_t)(gv * (s + s - 1.f));
        }
        __syncthreads();
        xg_cur = xg_nxt;
    }

    if (row < 64) {
        float p = (float)sh_h[row] * Wlin[row] +
                  (float)sh_h[row + 64] * Wlin[row + 64];
#pragma unroll
        for (int off = 32; off > 0; off >>= 1) p += __shfl_down(p, off);
        if (row == 0) out[0] = sigmoid_f(p + blin[0]);
    }
}

extern "C" void kernel_launch(void* const* d_in, const int* in_sizes, int n_in,
                              void* d_out, int out_size, void* d_ws, size_t ws_size,
                              hipStream_t stream)
{
    const float* x    = (const float*)d_in[0];
    const float* Wih  = (const float*)d_in[1];
    const float* Whh  = (const float*)d_in[2];
    const float* bih  = (const float*)d_in[3];
    const float* bhh  = (const float*)d_in[4];
    const float* Wlin = (const float*)d_in[5];
    const float* blin = (const float*)d_in[6];
    float* out = (float*)d_out;

    const size_t need = (size_t)SEQ * G4 * sizeof(float); // 128 MB
    if (ws_size >= need) {
        float* xg = (float*)d_ws;
        xg_gemm_t<<<SEQ / 16, 256, 0, stream>>>(x, Wih, bih, bhh, xg);
        lstm_scan<<<1, 256, 0, stream>>>(Whh, Wlin, blin, xg, out);
    } else {
        lstm_scan_fb<<<1, 512, 0, stream>>>(x, Wih, Whh, bih, bhh, Wlin,
                                            blin, out);
    }
}